// Round 1
// baseline (3280.577 us; speedup 1.0000x reference)
//
#include <hip/hip_runtime.h>
#include <math.h>

// Problem constants
constexpr int Bc = 4;
constexpr int Tc = 2048;
constexpr int Dc = 1024;
constexpr int Hc = 16;
constexpr int DHc = 64;
constexpr int Mc = Bc * Tc;          // 8192 rows
constexpr size_t QKV_ELEMS = (size_t)Bc * Hc * Tc * DHc;  // 8388608

// ---------------------------------------------------------------------------
// Kernel 1: fused QKV projection GEMM.  C[M=8192, N=1024] = x @ W{q,k,v}
// Output written permuted to [B][H][T][DH]; Q gets 1/sqrt(DH)=0.125 folded in.
// Tiles: BM=64, BN=64, BK=16; 256 threads, 4x4 per thread.
// ---------------------------------------------------------------------------
__global__ __launch_bounds__(256)
void qkv_proj_kernel(const float* __restrict__ x,
                     const float* __restrict__ Wq,
                     const float* __restrict__ Wk,
                     const float* __restrict__ Wv,
                     float* __restrict__ Q,
                     float* __restrict__ K,
                     float* __restrict__ V)
{
    const int z = blockIdx.z;
    const float* __restrict__ W = (z == 0) ? Wq : ((z == 1) ? Wk : Wv);
    float* __restrict__ out     = (z == 0) ? Q  : ((z == 1) ? K  : V);
    const float scale = (z == 0) ? 0.125f : 1.0f;

    __shared__ float As[16][68];   // [k][m], padded
    __shared__ float Bs[16][68];   // [k][n], padded

    const int tid = threadIdx.x;
    const int m0 = blockIdx.x * 64;
    const int n0 = blockIdx.y * 64;
    const int tr = tid / 16;       // 0..15
    const int tc = tid % 16;       // 0..15

    const int a_kc = tid % 16;     // k within tile
    const int a_r0 = tid / 16;     // row base (step 16)
    const int b_c  = tid % 64;     // n within tile
    const int b_r0 = tid / 64;     // k base (step 4)

    float acc[4][4] = {};

    for (int k0 = 0; k0 < Dc; k0 += 16) {
        #pragma unroll
        for (int i = 0; i < 4; ++i) {
            int r = a_r0 + i * 16;
            As[a_kc][r] = x[(size_t)(m0 + r) * Dc + k0 + a_kc];
        }
        #pragma unroll
        for (int i = 0; i < 4; ++i) {
            int r = b_r0 + i * 4;
            Bs[r][b_c] = W[(size_t)(k0 + r) * Dc + n0 + b_c];
        }
        __syncthreads();

        #pragma unroll
        for (int k = 0; k < 16; ++k) {
            float4 av = *reinterpret_cast<const float4*>(&As[k][tr * 4]);
            float4 bv = *reinterpret_cast<const float4*>(&Bs[k][tc * 4]);
            const float a_[4] = {av.x, av.y, av.z, av.w};
            const float b_[4] = {bv.x, bv.y, bv.z, bv.w};
            #pragma unroll
            for (int i = 0; i < 4; ++i)
                #pragma unroll
                for (int j = 0; j < 4; ++j)
                    acc[i][j] = fmaf(a_[i], b_[j], acc[i][j]);
        }
        __syncthreads();
    }

    // Store permuted: out[((b*H + h)*T + t)*DH + dh], h = blockIdx.y (BN==DH)
    const int h = blockIdx.y;
    #pragma unroll
    for (int i = 0; i < 4; ++i) {
        int m = m0 + tr * 4 + i;
        int b = m / Tc, t = m % Tc;
        float4 v = make_float4(acc[i][0] * scale, acc[i][1] * scale,
                               acc[i][2] * scale, acc[i][3] * scale);
        *reinterpret_cast<float4*>(
            &out[((size_t)(b * Hc + h) * Tc + t) * DHc + tc * 4]) = v;
    }
}

// ---------------------------------------------------------------------------
// Kernel 2: flash attention (causal), fp32.  One block per (bh, 64-query tile).
// Q/K/V layout: [BH][T][DH].  ctx written as [B][T][D] for the output GEMM.
// ---------------------------------------------------------------------------
__global__ __launch_bounds__(256)
void attn_kernel(const float* __restrict__ Q,
                 const float* __restrict__ K,
                 const float* __restrict__ V,
                 float* __restrict__ ctx)
{
    __shared__ float Qs[64][68];
    __shared__ float Ks[64][68];
    __shared__ float Vs[64][68];
    __shared__ float Ss[64][68];
    __shared__ float mS[64], lS[64], aS[64];

    const int tid = threadIdx.x;
    const int bh = blockIdx.y;                 // 0..63
    const int q0 = blockIdx.x * 64;
    const size_t base = (size_t)bh * Tc * DHc;

    // Load Q tile (64 rows x 64 floats), float4 per lane x4
    #pragma unroll
    for (int it = 0; it < 4; ++it) {
        int idx = tid + it * 256;              // float4 index 0..1023
        int row = idx / 16;
        int c4  = idx % 16;
        *reinterpret_cast<float4*>(&Qs[row][c4 * 4]) =
            *reinterpret_cast<const float4*>(&Q[base + (size_t)(q0 + row) * DHc + c4 * 4]);
    }
    if (tid < 64) { mS[tid] = -INFINITY; lS[tid] = 0.f; }

    const int tr = tid / 16;   // query sub-row group
    const int tc = tid % 16;   // key / dh sub-col group
    float acc[4][4] = {};

    const int ktiles = q0 / 64 + 1;
    for (int kt = 0; kt < ktiles; ++kt) {
        const int k0 = kt * 64;
        __syncthreads();   // previous iter's reads of Ks/Vs/Ss done; Qs/mS ready
        #pragma unroll
        for (int it = 0; it < 4; ++it) {
            int idx = tid + it * 256;
            int row = idx / 16;
            int c4  = idx % 16;
            *reinterpret_cast<float4*>(&Ks[row][c4 * 4]) =
                *reinterpret_cast<const float4*>(&K[base + (size_t)(k0 + row) * DHc + c4 * 4]);
            *reinterpret_cast<float4*>(&Vs[row][c4 * 4]) =
                *reinterpret_cast<const float4*>(&V[base + (size_t)(k0 + row) * DHc + c4 * 4]);
        }
        __syncthreads();

        // S = Q K^T  (64x64), 4x4 per thread, dot over DH=64
        float s[4][4] = {};
        #pragma unroll
        for (int d0 = 0; d0 < 16; ++d0) {
            float4 qv[4], kv[4];
            #pragma unroll
            for (int i = 0; i < 4; ++i)
                qv[i] = *reinterpret_cast<const float4*>(&Qs[tr * 4 + i][d0 * 4]);
            #pragma unroll
            for (int j = 0; j < 4; ++j)
                kv[j] = *reinterpret_cast<const float4*>(&Ks[tc * 4 + j][d0 * 4]);
            #pragma unroll
            for (int i = 0; i < 4; ++i)
                #pragma unroll
                for (int j = 0; j < 4; ++j) {
                    s[i][j] = fmaf(qv[i].x, kv[j].x, s[i][j]);
                    s[i][j] = fmaf(qv[i].y, kv[j].y, s[i][j]);
                    s[i][j] = fmaf(qv[i].z, kv[j].z, s[i][j]);
                    s[i][j] = fmaf(qv[i].w, kv[j].w, s[i][j]);
                }
        }

        // Causal mask on the diagonal tile
        if (k0 == q0) {
            #pragma unroll
            for (int i = 0; i < 4; ++i)
                #pragma unroll
                for (int j = 0; j < 4; ++j)
                    if (tc * 4 + j > tr * 4 + i) s[i][j] = -INFINITY;
        }

        #pragma unroll
        for (int i = 0; i < 4; ++i)
            *reinterpret_cast<float4*>(&Ss[tr * 4 + i][tc * 4]) =
                make_float4(s[i][0], s[i][1], s[i][2], s[i][3]);
        __syncthreads();

        // Online softmax row update (64 row-owner threads)
        if (tid < 64) {
            float mold = mS[tid], lold = lS[tid];
            float mrow = -INFINITY;
            #pragma unroll 8
            for (int c = 0; c < 64; ++c) mrow = fmaxf(mrow, Ss[tid][c]);
            float mnew  = fmaxf(mold, mrow);
            float alpha = __expf(mold - mnew);    // exp(-inf)=0 on first tile
            float lsum = 0.f;
            #pragma unroll 8
            for (int c = 0; c < 64; ++c) {
                float p = __expf(Ss[tid][c] - mnew);
                Ss[tid][c] = p;
                lsum += p;
            }
            mS[tid] = mnew;
            lS[tid] = lold * alpha + lsum;
            aS[tid] = alpha;
        }
        __syncthreads();

        // O = O*alpha + P @ V
        #pragma unroll
        for (int i = 0; i < 4; ++i) {
            float alpha = aS[tr * 4 + i];
            #pragma unroll
            for (int j = 0; j < 4; ++j) acc[i][j] *= alpha;
        }
        #pragma unroll
        for (int c0 = 0; c0 < 16; ++c0) {
            float4 pv[4], vv[4];
            #pragma unroll
            for (int i = 0; i < 4; ++i)
                pv[i] = *reinterpret_cast<const float4*>(&Ss[tr * 4 + i][c0 * 4]);
            #pragma unroll
            for (int cc = 0; cc < 4; ++cc)
                vv[cc] = *reinterpret_cast<const float4*>(&Vs[c0 * 4 + cc][tc * 4]);
            #pragma unroll
            for (int i = 0; i < 4; ++i) {
                const float pr[4] = {pv[i].x, pv[i].y, pv[i].z, pv[i].w};
                #pragma unroll
                for (int cc = 0; cc < 4; ++cc) {
                    const float* vp = reinterpret_cast<const float*>(&vv[cc]);
                    #pragma unroll
                    for (int j = 0; j < 4; ++j)
                        acc[i][j] = fmaf(pr[cc], vp[j], acc[i][j]);
                }
            }
        }
    }

    // Normalize and store ctx[b][t][h*64+dh]
    const int b = bh / Hc, h = bh % Hc;
    #pragma unroll
    for (int i = 0; i < 4; ++i) {
        int r = tr * 4 + i;
        float linv = 1.0f / lS[r];
        int t = q0 + r;
        float4 o = make_float4(acc[i][0] * linv, acc[i][1] * linv,
                               acc[i][2] * linv, acc[i][3] * linv);
        *reinterpret_cast<float4*>(
            &ctx[((size_t)(b * Tc + t)) * Dc + h * DHc + tc * 4]) = o;
    }
}

// ---------------------------------------------------------------------------
// Kernel 3: output projection GEMM + bias.  out[M,1024] = ctx @ Wo + bo
// ---------------------------------------------------------------------------
__global__ __launch_bounds__(256)
void out_proj_kernel(const float* __restrict__ ctx,
                     const float* __restrict__ Wo,
                     const float* __restrict__ bo,
                     float* __restrict__ out)
{
    __shared__ float As[16][68];
    __shared__ float Bs[16][68];

    const int tid = threadIdx.x;
    const int m0 = blockIdx.x * 64;
    const int n0 = blockIdx.y * 64;
    const int tr = tid / 16;
    const int tc = tid % 16;

    const int a_kc = tid % 16;
    const int a_r0 = tid / 16;
    const int b_c  = tid % 64;
    const int b_r0 = tid / 64;

    float acc[4][4] = {};

    for (int k0 = 0; k0 < Dc; k0 += 16) {
        #pragma unroll
        for (int i = 0; i < 4; ++i) {
            int r = a_r0 + i * 16;
            As[a_kc][r] = ctx[(size_t)(m0 + r) * Dc + k0 + a_kc];
        }
        #pragma unroll
        for (int i = 0; i < 4; ++i) {
            int r = b_r0 + i * 4;
            Bs[r][b_c] = Wo[(size_t)(k0 + r) * Dc + n0 + b_c];
        }
        __syncthreads();

        #pragma unroll
        for (int k = 0; k < 16; ++k) {
            float4 av = *reinterpret_cast<const float4*>(&As[k][tr * 4]);
            float4 bv = *reinterpret_cast<const float4*>(&Bs[k][tc * 4]);
            const float a_[4] = {av.x, av.y, av.z, av.w};
            const float b_[4] = {bv.x, bv.y, bv.z, bv.w};
            #pragma unroll
            for (int i = 0; i < 4; ++i)
                #pragma unroll
                for (int j = 0; j < 4; ++j)
                    acc[i][j] = fmaf(a_[i], b_[j], acc[i][j]);
        }
        __syncthreads();
    }

    #pragma unroll
    for (int i = 0; i < 4; ++i) {
        int m = m0 + tr * 4 + i;
        int n = n0 + tc * 4;
        float4 bv = *reinterpret_cast<const float4*>(&bo[n]);
        float4 v = make_float4(acc[i][0] + bv.x, acc[i][1] + bv.y,
                               acc[i][2] + bv.z, acc[i][3] + bv.w);
        *reinterpret_cast<float4*>(&out[(size_t)m * Dc + n]) = v;
    }
}

// ---------------------------------------------------------------------------
extern "C" void kernel_launch(void* const* d_in, const int* in_sizes, int n_in,
                              void* d_out, int out_size, void* d_ws, size_t ws_size,
                              hipStream_t stream)
{
    const float* x  = (const float*)d_in[0];
    const float* Wq = (const float*)d_in[1];
    const float* Wk = (const float*)d_in[2];
    const float* Wv = (const float*)d_in[3];
    const float* Wo = (const float*)d_in[4];
    const float* bo = (const float*)d_in[5];
    float* out = (float*)d_out;

    float* Q = (float*)d_ws;                 // [B,H,T,DH]
    float* K = Q + QKV_ELEMS;
    float* V = K + QKV_ELEMS;
    float* C = V + QKV_ELEMS;                // ctx [B,T,D]

    qkv_proj_kernel<<<dim3(Mc / 64, Dc / 64, 3), 256, 0, stream>>>(x, Wq, Wk, Wv, Q, K, V);
    attn_kernel<<<dim3(Tc / 64, Bc * Hc), 256, 0, stream>>>(Q, K, V, C);
    out_proj_kernel<<<dim3(Mc / 64, Dc / 64), 256, 0, stream>>>(C, Wo, bo, out);
}

// Round 4
// 401.804 us; speedup vs baseline: 8.1646x; 8.1646x over previous
//
#include <hip/hip_runtime.h>
#include <math.h>
#include <stdint.h>

typedef unsigned short u16;
typedef __bf16 bf16x8 __attribute__((ext_vector_type(8)));
typedef unsigned short u16x8 __attribute__((ext_vector_type(8)));
typedef float f32x4 __attribute__((ext_vector_type(4)));

constexpr int Tc = 2048, Dc = 1024, Hc = 16, Mc = 8192;
constexpr size_t NQKV = (size_t)Mc * Dc;   // 8388608
constexpr size_t NW = (size_t)Dc * Dc;     // 1048576

__device__ __forceinline__ u16 f2bf(float f) {
    union { float f; uint32_t u; } c; c.f = f;
    uint32_t u = c.u;
    u += 0x7FFFu + ((u >> 16) & 1u);       // RNE
    return (u16)(u >> 16);
}

__device__ __forceinline__ bf16x8 ldbf8(const u16* p) {
    u16x8 v = *(const u16x8*)p;
    return __builtin_bit_cast(bf16x8, v);
}

// global->LDS direct copy, 16B per lane. LDS dest is wave-uniform base;
// lane i lands at base + i*16B. Global side: AS1 shares representation with
// generic, so inttoptr is safe. LDS side: C-style cast -> addrspacecast
// (NEVER integer roundtrip: generic LDS addr = aperture | offset).
__device__ __forceinline__ void gload_lds16(const void* g, void* l) {
    __builtin_amdgcn_global_load_lds(
        (__attribute__((address_space(1))) void*)(uintptr_t)g,
        (__attribute__((address_space(3))) void*)l, 16, 0, 0);
}

// ---------------------------------------------------------------------------
// fp32 -> bf16 convert of x (8192x1024), 4 elems/thread
// ---------------------------------------------------------------------------
__global__ __launch_bounds__(256)
void cvt_x_kernel(const float* __restrict__ x, u16* __restrict__ xb)
{
    int i = blockIdx.x * 256 + threadIdx.x;        // float4 index
    float4 v = ((const float4*)x)[i];
    ushort4 o;
    o.x = f2bf(v.x); o.y = f2bf(v.y); o.z = f2bf(v.z); o.w = f2bf(v.w);
    ((ushort4*)xb)[i] = o;
}

// ---------------------------------------------------------------------------
// Weight transpose+convert: WT[n][k] = bf16(W[k][n]), for Wq,Wk,Wv,Wo (z)
// ---------------------------------------------------------------------------
__global__ __launch_bounds__(256)
void wt_cvt_kernel(const float* __restrict__ Wq, const float* __restrict__ Wk,
                   const float* __restrict__ Wv, const float* __restrict__ Wo,
                   u16* __restrict__ WTq, u16* __restrict__ WTk,
                   u16* __restrict__ WTv, u16* __restrict__ WTo)
{
    __shared__ float Ts[64][65];
    const int z = blockIdx.z;
    const float* W = (z == 0) ? Wq : (z == 1) ? Wk : (z == 2) ? Wv : Wo;
    u16* WT        = (z == 0) ? WTq : (z == 1) ? WTk : (z == 2) ? WTv : WTo;
    const int k0 = blockIdx.x * 64, n0 = blockIdx.y * 64;
    const int tid = threadIdx.x;
    #pragma unroll
    for (int it = 0; it < 16; ++it) {
        int flat = it * 256 + tid;
        int r = flat >> 6, c = flat & 63;
        Ts[r][c] = W[(size_t)(k0 + r) * Dc + n0 + c];
    }
    __syncthreads();
    #pragma unroll
    for (int it = 0; it < 16; ++it) {
        int flat = it * 256 + tid;
        int rn = flat >> 6, ck = flat & 63;
        WT[(size_t)(n0 + rn) * Dc + k0 + ck] = f2bf(Ts[ck][rn]);
    }
}

// ---------------------------------------------------------------------------
// bf16 MFMA GEMM (m97 structure): C[8192][1024] = A[8192][1024] x BT[1024][1024]^T
// 128x128 tile, BK=32, 4 waves (2x2), each wave 64x64 = 4x4 frags of 16x16x32.
// QKV variant: bf16 output permuted to [B*H][T][64]; Q scaled by 0.125.
// LDS chunk swizzle: slot = p ^ ((r>>1)&3)  -> 2-way (free) per 16-lane phase.
// ---------------------------------------------------------------------------
__global__ __launch_bounds__(256)
void qkv_gemm_kernel(const u16* __restrict__ xb,
                     const u16* __restrict__ WTq, const u16* __restrict__ WTk,
                     const u16* __restrict__ WTv,
                     u16* __restrict__ Qb, u16* __restrict__ Kb, u16* __restrict__ Vb)
{
    const int z = blockIdx.z;
    const u16* WT = (z == 0) ? WTq : (z == 1) ? WTk : WTv;
    u16* outp     = (z == 0) ? Qb  : (z == 1) ? Kb  : Vb;
    const float scale = (z == 0) ? 0.125f : 1.0f;

    __shared__ __align__(16) u16 As[128 * 32];
    __shared__ __align__(16) u16 Bs[128 * 32];

    const int tid = threadIdx.x, lane = tid & 63, w = tid >> 6;
    const int wm = w >> 1, wn = w & 1;
    const int m0 = blockIdx.x * 128, n0 = blockIdx.y * 128;

    f32x4 acc[4][4] = {};

    for (int k0 = 0; k0 < Dc; k0 += 32) {
        __syncthreads();
        #pragma unroll
        for (int t = 0; t < 2; ++t) {
            int ci = w * 64 + t * 256 + lane;          // 16B chunk id, 512 total
            int r = ci >> 2, p = ci & 3;               // row, chunk-in-row
            int pc = p ^ ((r >> 1) & 3);               // source pre-swizzle
            gload_lds16(xb + (size_t)(m0 + r) * Dc + k0 + pc * 8,
                        As + (size_t)(w * 64 + t * 256) * 8);
            gload_lds16(WT + (size_t)(n0 + r) * Dc + k0 + pc * 8,
                        Bs + (size_t)(w * 64 + t * 256) * 8);
        }
        __syncthreads();   // drains vmcnt before barrier

        bf16x8 a[4], b[4];
        #pragma unroll
        for (int i = 0; i < 4; ++i) {
            int row = wm * 64 + i * 16 + (lane & 15);
            a[i] = ldbf8(As + row * 32 + (((lane >> 4) ^ ((row >> 1) & 3)) * 8));
            int col = wn * 64 + i * 16 + (lane & 15);
            b[i] = ldbf8(Bs + col * 32 + (((lane >> 4) ^ ((col >> 1) & 3)) * 8));
        }
        #pragma unroll
        for (int i = 0; i < 4; ++i)
            #pragma unroll
            for (int j = 0; j < 4; ++j)
                acc[i][j] = __builtin_amdgcn_mfma_f32_16x16x32_bf16(a[i], b[j], acc[i][j], 0, 0, 0);
    }

    // Epilogue: permuted bf16 store to [B*H][T][64]
    #pragma unroll
    for (int j = 0; j < 4; ++j) {
        int n = n0 + wn * 64 + j * 16 + (lane & 15);
        int hh = n >> 6, dh = n & 63;
        #pragma unroll
        for (int i = 0; i < 4; ++i) {
            #pragma unroll
            for (int r = 0; r < 4; ++r) {
                int m = m0 + wm * 64 + i * 16 + (lane >> 4) * 4 + r;
                int bb = m >> 11, t = m & 2047;
                outp[((size_t)(bb * Hc + hh) * Tc + t) * 64 + dh] = f2bf(acc[i][j][r] * scale);
            }
        }
    }
}

// ---------------------------------------------------------------------------
// V transpose per bh: VT[bh][d][t] = V[bh][t][d]
// ---------------------------------------------------------------------------
__global__ __launch_bounds__(256)
void v_transpose_kernel(const u16* __restrict__ Vb, u16* __restrict__ VTb)
{
    __shared__ u16 Ts[64][68];
    const int tid = threadIdx.x;
    const int bh = blockIdx.y, t0 = blockIdx.x * 64;
    const size_t vbase = (size_t)bh * Tc * 64;
    #pragma unroll
    for (int it = 0; it < 4; ++it) {
        int flat = it * 1024 + tid * 4;
        int r = flat >> 6, c = flat & 63;
        *(ushort4*)&Ts[r][c] = *(const ushort4*)(Vb + vbase + (size_t)(t0 + r) * 64 + c);
    }
    __syncthreads();
    const size_t obase = (size_t)bh * 64 * Tc;
    #pragma unroll
    for (int it = 0; it < 4; ++it) {
        int flat = it * 1024 + tid * 4;
        int d = flat >> 6, tl = flat & 63;
        ushort4 o;
        o.x = Ts[tl][d]; o.y = Ts[tl + 1][d]; o.z = Ts[tl + 2][d]; o.w = Ts[tl + 3][d];
        *(ushort4*)(VTb + obase + (size_t)d * Tc + t0 + tl) = o;
    }
}

// ---------------------------------------------------------------------------
// MFMA flash attention (causal). Block = 256 thr (4 waves), QBLK=128 (32 q/wave),
// KVBLK=64. Q in registers; K and VT tiles staged via gload_lds with source
// pre-swizzle (chunk ^= row&7) so ds_read_b128 is 2-way (free). Softmax fully
// in-register via shfl_xor over the 16-lane col group; P transposed via
// per-wave LDS (stride 72) for the PV A-fragment.
// ---------------------------------------------------------------------------
__global__ __launch_bounds__(256)
void attn_mfma_kernel(const u16* __restrict__ Qb, const u16* __restrict__ Kb,
                      const u16* __restrict__ VTb, u16* __restrict__ ctxb)
{
    __shared__ __align__(16) u16 Ks[64 * 64];
    __shared__ __align__(16) u16 Vs[64 * 64];
    __shared__ __align__(16) u16 Ps[4][32 * 72];

    const int tid = threadIdx.x, lane = tid & 63, w = tid >> 6;
    const int bh = blockIdx.y;
    const int q0 = blockIdx.x * 128;
    const int nkt = (q0 >> 6) + 2;                     // kv tiles to process
    const size_t qkbase = (size_t)bh * Tc * 64;
    const size_t vtbase = (size_t)bh * 64 * Tc;

    // Q fragments in registers (scaled by 0.125 already)
    bf16x8 qf[2][2];
    #pragma unroll
    for (int mi = 0; mi < 2; ++mi)
        #pragma unroll
        for (int kf = 0; kf < 2; ++kf) {
            int row = q0 + w * 32 + mi * 16 + (lane & 15);
            qf[mi][kf] = ldbf8(Qb + qkbase + (size_t)row * 64 + kf * 32 + (lane >> 4) * 8);
        }

    f32x4 o_acc[2][4] = {};
    float m_run[2][4], l_run[2][4];
    #pragma unroll
    for (int mi = 0; mi < 2; ++mi)
        #pragma unroll
        for (int r = 0; r < 4; ++r) { m_run[mi][r] = -INFINITY; l_run[mi][r] = 0.f; }

    for (int kt = 0; kt < nkt; ++kt) {
        const int kv0 = kt * 64;
        __syncthreads();
        // stage K (rows kv, cols dh) and VT (rows dh, cols t) tiles, swizzled src
        #pragma unroll
        for (int t = 0; t < 2; ++t) {
            int ci = w * 64 + t * 256 + lane;          // chunk 0..511
            int r = ci >> 3, p = ci & 7;
            int pc = p ^ (r & 7);
            gload_lds16(Kb + qkbase + (size_t)(kv0 + r) * 64 + pc * 8,
                        Ks + (size_t)(w * 64 + t * 256) * 8);
            gload_lds16(VTb + vtbase + (size_t)r * Tc + kv0 + pc * 8,
                        Vs + (size_t)(w * 64 + t * 256) * 8);
        }
        __syncthreads();

        // S = Q K^T  (2 mi x 4 ni fragments)
        f32x4 s[2][4] = {};
        #pragma unroll
        for (int kf = 0; kf < 2; ++kf) {
            bf16x8 kb[4];
            #pragma unroll
            for (int ni = 0; ni < 4; ++ni) {
                int rr = ni * 16 + (lane & 15);
                int pc = ((lane >> 4) + 4 * kf) ^ (rr & 7);
                kb[ni] = ldbf8(Ks + rr * 64 + pc * 8);
            }
            #pragma unroll
            for (int mi = 0; mi < 2; ++mi)
                #pragma unroll
                for (int ni = 0; ni < 4; ++ni)
                    s[mi][ni] = __builtin_amdgcn_mfma_f32_16x16x32_bf16(qf[mi][kf], kb[ni], s[mi][ni], 0, 0, 0);
        }

        // causal mask (only last two tiles can hit the diagonal)
        if (kt >= nkt - 2) {
            #pragma unroll
            for (int mi = 0; mi < 2; ++mi)
                #pragma unroll
                for (int ni = 0; ni < 4; ++ni)
                    #pragma unroll
                    for (int r = 0; r < 4; ++r) {
                        int qrow = q0 + w * 32 + mi * 16 + (lane >> 4) * 4 + r;
                        int kcol = kv0 + ni * 16 + (lane & 15);
                        if (kcol > qrow) s[mi][ni][r] = -INFINITY;
                    }
        }

        // online softmax, in-register (rows live in 16-lane col groups)
        #pragma unroll
        for (int mi = 0; mi < 2; ++mi) {
            #pragma unroll
            for (int r = 0; r < 4; ++r) {
                float v = fmaxf(fmaxf(s[mi][0][r], s[mi][1][r]),
                                fmaxf(s[mi][2][r], s[mi][3][r]));
                #pragma unroll
                for (int off = 1; off < 16; off <<= 1)
                    v = fmaxf(v, __shfl_xor(v, off, 64));
                float mnew = fmaxf(m_run[mi][r], v);
                float alpha = __expf(m_run[mi][r] - mnew);
                m_run[mi][r] = mnew;
                float sum = 0.f;
                #pragma unroll
                for (int ni = 0; ni < 4; ++ni) {
                    float p = __expf(s[mi][ni][r] - mnew);
                    s[mi][ni][r] = p;
                    sum += p;
                }
                #pragma unroll
                for (int off = 1; off < 16; off <<= 1)
                    sum += __shfl_xor(sum, off, 64);
                l_run[mi][r] = l_run[mi][r] * alpha + sum;
                #pragma unroll
                for (int nd = 0; nd < 4; ++nd) o_acc[mi][nd][r] *= alpha;
            }
        }

        // P -> per-wave LDS (transpose for PV A-fragment)
        u16* pw = &Ps[w][0];
        #pragma unroll
        for (int mi = 0; mi < 2; ++mi)
            #pragma unroll
            for (int ni = 0; ni < 4; ++ni)
                #pragma unroll
                for (int r = 0; r < 4; ++r) {
                    int row = mi * 16 + (lane >> 4) * 4 + r;
                    int col = ni * 16 + (lane & 15);
                    pw[row * 72 + col] = f2bf(s[mi][ni][r]);
                }

        // PV: o += P[32q x 64kv] @ V[64kv x 64dh]  (B^T = VT tile)
        bf16x8 pa[2][2];
        #pragma unroll
        for (int mi = 0; mi < 2; ++mi)
            #pragma unroll
            for (int kf = 0; kf < 2; ++kf)
                pa[mi][kf] = ldbf8(pw + (mi * 16 + (lane & 15)) * 72 + kf * 32 + (lane >> 4) * 8);
        #pragma unroll
        for (int kf = 0; kf < 2; ++kf) {
            bf16x8 vb[4];
            #pragma unroll
            for (int nd = 0; nd < 4; ++nd) {
                int rr = nd * 16 + (lane & 15);
                int pc = ((lane >> 4) + 4 * kf) ^ (rr & 7);
                vb[nd] = ldbf8(Vs + rr * 64 + pc * 8);
            }
            #pragma unroll
            for (int mi = 0; mi < 2; ++mi)
                #pragma unroll
                for (int nd = 0; nd < 4; ++nd)
                    o_acc[mi][nd] = __builtin_amdgcn_mfma_f32_16x16x32_bf16(pa[mi][kf], vb[nd], o_acc[mi][nd], 0, 0, 0);
        }
    }

    // normalize + store ctx [B][T][D] bf16
    const int b = bh >> 4, h = bh & 15;
    #pragma unroll
    for (int mi = 0; mi < 2; ++mi)
        #pragma unroll
        for (int r = 0; r < 4; ++r) {
            float inv = 1.0f / l_run[mi][r];
            int qrow = q0 + w * 32 + mi * 16 + (lane >> 4) * 4 + r;
            #pragma unroll
            for (int nd = 0; nd < 4; ++nd) {
                int d = h * 64 + nd * 16 + (lane & 15);
                ctxb[(size_t)(b * Tc + qrow) * Dc + d] = f2bf(o_acc[mi][nd][r] * inv);
            }
        }
}

// ---------------------------------------------------------------------------
// Output projection: out[8192][1024] = ctx @ Wo + bo   (f32 out)
// ---------------------------------------------------------------------------
__global__ __launch_bounds__(256)
void out_gemm_kernel(const u16* __restrict__ ctxb, const u16* __restrict__ WTo,
                     const float* __restrict__ bo, float* __restrict__ out)
{
    __shared__ __align__(16) u16 As[128 * 32];
    __shared__ __align__(16) u16 Bs[128 * 32];

    const int tid = threadIdx.x, lane = tid & 63, w = tid >> 6;
    const int wm = w >> 1, wn = w & 1;
    const int m0 = blockIdx.x * 128, n0 = blockIdx.y * 128;

    f32x4 acc[4][4] = {};

    for (int k0 = 0; k0 < Dc; k0 += 32) {
        __syncthreads();
        #pragma unroll
        for (int t = 0; t < 2; ++t) {
            int ci = w * 64 + t * 256 + lane;
            int r = ci >> 2, p = ci & 3;
            int pc = p ^ ((r >> 1) & 3);
            gload_lds16(ctxb + (size_t)(m0 + r) * Dc + k0 + pc * 8,
                        As + (size_t)(w * 64 + t * 256) * 8);
            gload_lds16(WTo + (size_t)(n0 + r) * Dc + k0 + pc * 8,
                        Bs + (size_t)(w * 64 + t * 256) * 8);
        }
        __syncthreads();

        bf16x8 a[4], b[4];
        #pragma unroll
        for (int i = 0; i < 4; ++i) {
            int row = wm * 64 + i * 16 + (lane & 15);
            a[i] = ldbf8(As + row * 32 + (((lane >> 4) ^ ((row >> 1) & 3)) * 8));
            int col = wn * 64 + i * 16 + (lane & 15);
            b[i] = ldbf8(Bs + col * 32 + (((lane >> 4) ^ ((col >> 1) & 3)) * 8));
        }
        #pragma unroll
        for (int i = 0; i < 4; ++i)
            #pragma unroll
            for (int j = 0; j < 4; ++j)
                acc[i][j] = __builtin_amdgcn_mfma_f32_16x16x32_bf16(a[i], b[j], acc[i][j], 0, 0, 0);
    }

    #pragma unroll
    for (int j = 0; j < 4; ++j) {
        int n = n0 + wn * 64 + j * 16 + (lane & 15);
        float bias = bo[n];
        #pragma unroll
        for (int i = 0; i < 4; ++i) {
            #pragma unroll
            for (int r = 0; r < 4; ++r) {
                int m = m0 + wm * 64 + i * 16 + (lane >> 4) * 4 + r;
                out[(size_t)m * Dc + n] = acc[i][j][r] + bias;
            }
        }
    }
}

// ---------------------------------------------------------------------------
extern "C" void kernel_launch(void* const* d_in, const int* in_sizes, int n_in,
                              void* d_out, int out_size, void* d_ws, size_t ws_size,
                              hipStream_t stream)
{
    const float* x  = (const float*)d_in[0];
    const float* Wq = (const float*)d_in[1];
    const float* Wk = (const float*)d_in[2];
    const float* Wv = (const float*)d_in[3];
    const float* Wo = (const float*)d_in[4];
    const float* bo = (const float*)d_in[5];
    float* out = (float*)d_out;

    u16* xb   = (u16*)d_ws;            // [8192][1024]
    u16* WTq  = xb + NQKV;             // [1024][1024] (n-major)
    u16* WTk  = WTq + NW;
    u16* WTv  = WTk + NW;
    u16* WTo  = WTv + NW;
    u16* Qb   = WTo + NW;              // [BH][T][64], pre-scaled
    u16* Kb   = Qb + NQKV;
    u16* Vb   = Kb + NQKV;
    u16* VTb  = Vb + NQKV;             // [BH][64][T]
    u16* ctxb = VTb + NQKV;            // [B][T][D]

    cvt_x_kernel<<<8192, 256, 0, stream>>>(x, xb);
    wt_cvt_kernel<<<dim3(16, 16, 4), 256, 0, stream>>>(Wq, Wk, Wv, Wo, WTq, WTk, WTv, WTo);
    qkv_gemm_kernel<<<dim3(64, 8, 3), 256, 0, stream>>>(xb, WTq, WTk, WTv, Qb, Kb, Vb);
    v_transpose_kernel<<<dim3(32, 64), 256, 0, stream>>>(Vb, VTb);
    attn_mfma_kernel<<<dim3(16, 64), 256, 0, stream>>>(Qb, Kb, VTb, ctxb);
    out_gemm_kernel<<<dim3(64, 8), 256, 0, stream>>>(ctxb, WTo, bo, out);
}

// Round 8
// 272.210 us; speedup vs baseline: 12.0517x; 1.4761x over previous
//
#include <hip/hip_runtime.h>
#include <math.h>
#include <stdint.h>

typedef unsigned short u16;
typedef __bf16 bf16x8 __attribute__((ext_vector_type(8)));
typedef unsigned short u16x8 __attribute__((ext_vector_type(8)));
typedef float f32x4 __attribute__((ext_vector_type(4)));

constexpr int Tc = 2048, Dc = 1024, Hc = 16, Mc = 8192;
constexpr size_t NQKV = (size_t)Mc * Dc;   // 8388608
constexpr size_t NW = (size_t)Dc * Dc;     // 1048576

__device__ __forceinline__ u16 f2bf(float f) {
    union { float f; uint32_t u; } c; c.f = f;
    uint32_t u = c.u;
    u += 0x7FFFu + ((u >> 16) & 1u);       // RNE
    return (u16)(u >> 16);
}

__device__ __forceinline__ bf16x8 ldbf8(const u16* p) {
    u16x8 v = *(const u16x8*)p;
    return __builtin_bit_cast(bf16x8, v);
}

// global->LDS direct copy, 16B per lane. LDS dest is wave-uniform base;
// lane i lands at base + i*16B.
__device__ __forceinline__ void gload_lds16(const void* g, void* l) {
    __builtin_amdgcn_global_load_lds(
        (__attribute__((address_space(1))) void*)(uintptr_t)g,
        (__attribute__((address_space(3))) void*)l, 16, 0, 0);
}

// ---------------------------------------------------------------------------
// fp32 -> bf16 convert of x (8192x1024), 4 elems/thread
// ---------------------------------------------------------------------------
__global__ __launch_bounds__(256)
void cvt_x_kernel(const float* __restrict__ x, u16* __restrict__ xb)
{
    int i = blockIdx.x * 256 + threadIdx.x;        // float4 index
    float4 v = ((const float4*)x)[i];
    ushort4 o;
    o.x = f2bf(v.x); o.y = f2bf(v.y); o.z = f2bf(v.z); o.w = f2bf(v.w);
    ((ushort4*)xb)[i] = o;
}

// ---------------------------------------------------------------------------
// Weight transpose+convert: WT[n][k] = bf16(W[k][n]), for Wq,Wk,Wv,Wo (z)
// ---------------------------------------------------------------------------
__global__ __launch_bounds__(256)
void wt_cvt_kernel(const float* __restrict__ Wq, const float* __restrict__ Wk,
                   const float* __restrict__ Wv, const float* __restrict__ Wo,
                   u16* __restrict__ WTq, u16* __restrict__ WTk,
                   u16* __restrict__ WTv, u16* __restrict__ WTo)
{
    __shared__ float Ts[64][65];
    const int z = blockIdx.z;
    const float* W = (z == 0) ? Wq : (z == 1) ? Wk : (z == 2) ? Wv : Wo;
    u16* WT        = (z == 0) ? WTq : (z == 1) ? WTk : (z == 2) ? WTv : WTo;
    const int k0 = blockIdx.x * 64, n0 = blockIdx.y * 64;
    const int tid = threadIdx.x;
    #pragma unroll
    for (int it = 0; it < 16; ++it) {
        int flat = it * 256 + tid;
        int r = flat >> 6, c = flat & 63;
        Ts[r][c] = W[(size_t)(k0 + r) * Dc + n0 + c];
    }
    __syncthreads();
    #pragma unroll
    for (int it = 0; it < 16; ++it) {
        int flat = it * 256 + tid;
        int rn = flat >> 6, ck = flat & 63;
        WT[(size_t)(n0 + rn) * Dc + k0 + ck] = f2bf(Ts[ck][rn]);
    }
}

// ---------------------------------------------------------------------------
// bf16 MFMA GEMM (m97 structure): C[8192][1024] = A[8192][1024] x BT[1024][1024]^T
// 128x128 tile, BK=32, 4 waves (2x2), each wave 64x64 = 4x4 frags of 16x16x32.
// QKV variant: bf16 output permuted to [B*H][T][64]; Q scaled by 0.125.
// ---------------------------------------------------------------------------
__global__ __launch_bounds__(256)
void qkv_gemm_kernel(const u16* __restrict__ xb,
                     const u16* __restrict__ WTq, const u16* __restrict__ WTk,
                     const u16* __restrict__ WTv,
                     u16* __restrict__ Qb, u16* __restrict__ Kb, u16* __restrict__ Vb)
{
    const int z = blockIdx.z;
    const u16* WT = (z == 0) ? WTq : (z == 1) ? WTk : WTv;
    u16* outp     = (z == 0) ? Qb  : (z == 1) ? Kb  : Vb;
    const float scale = (z == 0) ? 0.125f : 1.0f;

    __shared__ __align__(16) u16 As[128 * 32];
    __shared__ __align__(16) u16 Bs[128 * 32];

    const int tid = threadIdx.x, lane = tid & 63, w = tid >> 6;
    const int wm = w >> 1, wn = w & 1;
    const int m0 = blockIdx.x * 128, n0 = blockIdx.y * 128;

    f32x4 acc[4][4] = {};

    for (int k0 = 0; k0 < Dc; k0 += 32) {
        __syncthreads();
        #pragma unroll
        for (int t = 0; t < 2; ++t) {
            int ci = w * 64 + t * 256 + lane;          // 16B chunk id, 512 total
            int r = ci >> 2, p = ci & 3;               // row, chunk-in-row
            int pc = p ^ ((r >> 1) & 3);               // source pre-swizzle
            gload_lds16(xb + (size_t)(m0 + r) * Dc + k0 + pc * 8,
                        As + (size_t)(w * 64 + t * 256) * 8);
            gload_lds16(WT + (size_t)(n0 + r) * Dc + k0 + pc * 8,
                        Bs + (size_t)(w * 64 + t * 256) * 8);
        }
        __syncthreads();   // drains vmcnt before barrier

        bf16x8 a[4], b[4];
        #pragma unroll
        for (int i = 0; i < 4; ++i) {
            int row = wm * 64 + i * 16 + (lane & 15);
            a[i] = ldbf8(As + row * 32 + (((lane >> 4) ^ ((row >> 1) & 3)) * 8));
            int col = wn * 64 + i * 16 + (lane & 15);
            b[i] = ldbf8(Bs + col * 32 + (((lane >> 4) ^ ((col >> 1) & 3)) * 8));
        }
        #pragma unroll
        for (int i = 0; i < 4; ++i)
            #pragma unroll
            for (int j = 0; j < 4; ++j)
                acc[i][j] = __builtin_amdgcn_mfma_f32_16x16x32_bf16(a[i], b[j], acc[i][j], 0, 0, 0);
    }

    // Epilogue: permuted bf16 store to [B*H][T][64]
    #pragma unroll
    for (int j = 0; j < 4; ++j) {
        int n = n0 + wn * 64 + j * 16 + (lane & 15);
        int hh = n >> 6, dh = n & 63;
        #pragma unroll
        for (int i = 0; i < 4; ++i) {
            #pragma unroll
            for (int r = 0; r < 4; ++r) {
                int m = m0 + wm * 64 + i * 16 + (lane >> 4) * 4 + r;
                int bb = m >> 11, t = m & 2047;
                outp[((size_t)(bb * Hc + hh) * Tc + t) * 64 + dh] = f2bf(acc[i][j][r] * scale);
            }
        }
    }
}

// ---------------------------------------------------------------------------
// V transpose per bh: VT[bh][d][t] = V[bh][t][d]
// ---------------------------------------------------------------------------
__global__ __launch_bounds__(256)
void v_transpose_kernel(const u16* __restrict__ Vb, u16* __restrict__ VTb)
{
    __shared__ u16 Ts[64][68];
    const int tid = threadIdx.x;
    const int bh = blockIdx.y, t0 = blockIdx.x * 64;
    const size_t vbase = (size_t)bh * Tc * 64;
    #pragma unroll
    for (int it = 0; it < 4; ++it) {
        int flat = it * 1024 + tid * 4;
        int r = flat >> 6, c = flat & 63;
        *(ushort4*)&Ts[r][c] = *(const ushort4*)(Vb + vbase + (size_t)(t0 + r) * 64 + c);
    }
    __syncthreads();
    const size_t obase = (size_t)bh * 64 * Tc;
    #pragma unroll
    for (int it = 0; it < 4; ++it) {
        int flat = it * 1024 + tid * 4;
        int d = flat >> 6, tl = flat & 63;
        ushort4 o;
        o.x = Ts[tl][d]; o.y = Ts[tl + 1][d]; o.z = Ts[tl + 2][d]; o.w = Ts[tl + 3][d];
        *(ushort4*)(VTb + obase + (size_t)d * Tc + t0 + tl) = o;
    }
}

// ---------------------------------------------------------------------------
// MFMA flash attention (causal), swapped-QK^T + balanced q-tile pairing.
// Grid (8, 64): block i handles q-tiles i and 15-i sequentially -> every
// block processes exactly 34 kv-tiles (load-balanced; 2 blocks/CU uniform).
// Swapped S^T = mfma(K, Q) puts each q-column in one lane: softmax is
// 15 in-lane fmax + 2 shfl_xor; P packed with v_cvt_pk_bf16_f32 ->
// ds_write_b64 (8 stores/tile), read back as PV A-frags via ds_read_b128.
// ---------------------------------------------------------------------------
__global__ __launch_bounds__(256)
void attn_mfma_kernel(const u16* __restrict__ Qb, const u16* __restrict__ Kb,
                      const u16* __restrict__ VTb, u16* __restrict__ ctxb)
{
    __shared__ __align__(16) u16 Ks[64 * 64];
    __shared__ __align__(16) u16 Vs[64 * 64];
    __shared__ __align__(16) u16 Ps[4][32 * 72];   // per-wave [q 0..31][kv 0..63] stride 72

    const int tid = threadIdx.x, lane = tid & 63, w = tid >> 6;
    const int g = lane >> 4, lq = lane & 15;
    const int bh = blockIdx.y;
    const size_t qkbase = (size_t)bh * Tc * 64;
    const size_t vtbase = (size_t)bh * 64 * Tc;
    const int b = bh >> 4, h = bh & 15;
    u16* pw = &Ps[w][0];

    #pragma unroll 1
    for (int pass = 0; pass < 2; ++pass) {
        const int qt = pass ? (15 - blockIdx.x) : blockIdx.x;
        const int q0 = qt * 128;
        const int nkt = qt * 2 + 2;                // kv tiles for this q-tile

        // Q fragments (B-operand: col=q=lq, k=dh), pre-scaled by 0.125
        bf16x8 qf[2][2];
        #pragma unroll
        for (int qfi = 0; qfi < 2; ++qfi)
            #pragma unroll
            for (int kf = 0; kf < 2; ++kf) {
                int row = q0 + w * 32 + qfi * 16 + lq;
                qf[qfi][kf] = ldbf8(Qb + qkbase + (size_t)row * 64 + kf * 32 + g * 8);
            }

        f32x4 o_acc[2][4] = {};
        float m_run[2] = {-INFINITY, -INFINITY};
        float l_run[2] = {0.f, 0.f};

        for (int kt = 0; kt < nkt; ++kt) {
            const int kv0 = kt * 64;
            __syncthreads();
            // stage K (rows kv, cols dh) and VT (rows dh, cols t), swizzled src
            #pragma unroll
            for (int t = 0; t < 2; ++t) {
                int ci = w * 64 + t * 256 + lane;          // chunk 0..511
                int r = ci >> 3, p = ci & 7;
                int pc = p ^ (r & 7);
                gload_lds16(Kb + qkbase + (size_t)(kv0 + r) * 64 + pc * 8,
                            Ks + (size_t)(w * 64 + t * 256) * 8);
                gload_lds16(VTb + vtbase + (size_t)r * Tc + kv0 + pc * 8,
                            Vs + (size_t)(w * 64 + t * 256) * 8);
            }
            __syncthreads();

            // S^T = K Q^T: D[kv][q]  (4 kv-frags x 2 q-frags)
            f32x4 s[4][2] = {};
            #pragma unroll
            for (int kf = 0; kf < 2; ++kf) {
                bf16x8 kb[4];
                #pragma unroll
                for (int ni = 0; ni < 4; ++ni) {
                    int rr = ni * 16 + lq;
                    int pc = (g + 4 * kf) ^ (rr & 7);
                    kb[ni] = ldbf8(Ks + rr * 64 + pc * 8);
                }
                #pragma unroll
                for (int ni = 0; ni < 4; ++ni)
                    #pragma unroll
                    for (int qfi = 0; qfi < 2; ++qfi)
                        s[ni][qfi] = __builtin_amdgcn_mfma_f32_16x16x32_bf16(kb[ni], qf[qfi][kf], s[ni][qfi], 0, 0, 0);
            }

            // causal mask: kv > q -> -inf (only last two tiles can straddle)
            if (kt >= nkt - 2) {
                #pragma unroll
                for (int ni = 0; ni < 4; ++ni)
                    #pragma unroll
                    for (int qfi = 0; qfi < 2; ++qfi)
                        #pragma unroll
                        for (int r = 0; r < 4; ++r) {
                            int kv = kv0 + ni * 16 + 4 * g + r;
                            int q  = q0 + w * 32 + qfi * 16 + lq;
                            if (kv > q) s[ni][qfi][r] = -INFINITY;
                        }
            }

            // online softmax: per lane = one q-column with 16 kv values
            #pragma unroll
            for (int qfi = 0; qfi < 2; ++qfi) {
                float mrow = -INFINITY;
                #pragma unroll
                for (int ni = 0; ni < 4; ++ni)
                    #pragma unroll
                    for (int r = 0; r < 4; ++r) mrow = fmaxf(mrow, s[ni][qfi][r]);
                mrow = fmaxf(mrow, __shfl_xor(mrow, 16, 64));
                mrow = fmaxf(mrow, __shfl_xor(mrow, 32, 64));
                float mnew  = fmaxf(m_run[qfi], mrow);
                float alpha = __expf(m_run[qfi] - mnew);   // exp(-inf)=0 first tile
                m_run[qfi] = mnew;
                float sum = 0.f;
                #pragma unroll
                for (int ni = 0; ni < 4; ++ni)
                    #pragma unroll
                    for (int r = 0; r < 4; ++r) {
                        float p = __expf(s[ni][qfi][r] - mnew);
                        s[ni][qfi][r] = p;
                        sum += p;
                    }
                sum += __shfl_xor(sum, 16, 64);
                sum += __shfl_xor(sum, 32, 64);
                l_run[qfi] = l_run[qfi] * alpha + sum;
                // redistribute alpha (held at lane lq==q) to o_acc rows (4g+r)
                #pragma unroll
                for (int r = 0; r < 4; ++r) {
                    float ar = __shfl(alpha, 4 * g + r, 16);
                    #pragma unroll
                    for (int nd = 0; nd < 4; ++nd) o_acc[qfi][nd][r] *= ar;
                }
            }

            // pack P -> per-wave LDS: row q_local, cols kv (stride 72 u16)
            #pragma unroll
            for (int qfi = 0; qfi < 2; ++qfi)
                #pragma unroll
                for (int ni = 0; ni < 4; ++ni) {
                    float a0 = s[ni][qfi][0], a1 = s[ni][qfi][1];
                    float a2 = s[ni][qfi][2], a3 = s[ni][qfi][3];
                    uint32_t lo, hi;
                    asm volatile("v_cvt_pk_bf16_f32 %0, %1, %2" : "=v"(lo) : "v"(a0), "v"(a1));
                    asm volatile("v_cvt_pk_bf16_f32 %0, %1, %2" : "=v"(hi) : "v"(a2), "v"(a3));
                    uint2 pk = make_uint2(lo, hi);
                    *(uint2*)(pw + (qfi * 16 + lq) * 72 + ni * 16 + 4 * g) = pk;
                }

            // PV: o[q][dh] += P[q][kv] V[kv][dh]; A=P from LDS, B=VT tile
            bf16x8 pa[2][2];
            #pragma unroll
            for (int qfi = 0; qfi < 2; ++qfi)
                #pragma unroll
                for (int kf = 0; kf < 2; ++kf)
                    pa[qfi][kf] = ldbf8(pw + (qfi * 16 + lq) * 72 + kf * 32 + 8 * g);
            #pragma unroll
            for (int kf = 0; kf < 2; ++kf) {
                bf16x8 vb[4];
                #pragma unroll
                for (int nd = 0; nd < 4; ++nd) {
                    int rr = nd * 16 + lq;
                    int pc = (g + 4 * kf) ^ (rr & 7);
                    vb[nd] = ldbf8(Vs + rr * 64 + pc * 8);
                }
                #pragma unroll
                for (int qfi = 0; qfi < 2; ++qfi)
                    #pragma unroll
                    for (int nd = 0; nd < 4; ++nd)
                        o_acc[qfi][nd] = __builtin_amdgcn_mfma_f32_16x16x32_bf16(pa[qfi][kf], vb[nd], o_acc[qfi][nd], 0, 0, 0);
            }
        }

        // normalize + store ctx [B][T][D] bf16 (l held at lane lq==q)
        #pragma unroll
        for (int qfi = 0; qfi < 2; ++qfi)
            #pragma unroll
            for (int r = 0; r < 4; ++r) {
                float lr = __shfl(l_run[qfi], 4 * g + r, 16);
                float inv = 1.0f / lr;
                int qrow = q0 + w * 32 + qfi * 16 + 4 * g + r;
                #pragma unroll
                for (int nd = 0; nd < 4; ++nd) {
                    int d = h * 64 + nd * 16 + lq;
                    ctxb[(size_t)(b * Tc + qrow) * Dc + d] = f2bf(o_acc[qfi][nd][r] * inv);
                }
            }
    }
}

// ---------------------------------------------------------------------------
// Output projection: out[8192][1024] = ctx @ Wo + bo   (f32 out)
// ---------------------------------------------------------------------------
__global__ __launch_bounds__(256)
void out_gemm_kernel(const u16* __restrict__ ctxb, const u16* __restrict__ WTo,
                     const float* __restrict__ bo, float* __restrict__ out)
{
    __shared__ __align__(16) u16 As[128 * 32];
    __shared__ __align__(16) u16 Bs[128 * 32];

    const int tid = threadIdx.x, lane = tid & 63, w = tid >> 6;
    const int wm = w >> 1, wn = w & 1;
    const int m0 = blockIdx.x * 128, n0 = blockIdx.y * 128;

    f32x4 acc[4][4] = {};

    for (int k0 = 0; k0 < Dc; k0 += 32) {
        __syncthreads();
        #pragma unroll
        for (int t = 0; t < 2; ++t) {
            int ci = w * 64 + t * 256 + lane;
            int r = ci >> 2, p = ci & 3;
            int pc = p ^ ((r >> 1) & 3);
            gload_lds16(ctxb + (size_t)(m0 + r) * Dc + k0 + pc * 8,
                        As + (size_t)(w * 64 + t * 256) * 8);
            gload_lds16(WTo + (size_t)(n0 + r) * Dc + k0 + pc * 8,
                        Bs + (size_t)(w * 64 + t * 256) * 8);
        }
        __syncthreads();

        bf16x8 a[4], b[4];
        #pragma unroll
        for (int i = 0; i < 4; ++i) {
            int row = wm * 64 + i * 16 + (lane & 15);
            a[i] = ldbf8(As + row * 32 + (((lane >> 4) ^ ((row >> 1) & 3)) * 8));
            int col = wn * 64 + i * 16 + (lane & 15);
            b[i] = ldbf8(Bs + col * 32 + (((lane >> 4) ^ ((col >> 1) & 3)) * 8));
        }
        #pragma unroll
        for (int i = 0; i < 4; ++i)
            #pragma unroll
            for (int j = 0; j < 4; ++j)
                acc[i][j] = __builtin_amdgcn_mfma_f32_16x16x32_bf16(a[i], b[j], acc[i][j], 0, 0, 0);
    }

    #pragma unroll
    for (int j = 0; j < 4; ++j) {
        int n = n0 + wn * 64 + j * 16 + (lane & 15);
        float bias = bo[n];
        #pragma unroll
        for (int i = 0; i < 4; ++i) {
            #pragma unroll
            for (int r = 0; r < 4; ++r) {
                int m = m0 + wm * 64 + i * 16 + (lane >> 4) * 4 + r;
                out[(size_t)m * Dc + n] = acc[i][j][r] + bias;
            }
        }
    }
}

// ---------------------------------------------------------------------------
extern "C" void kernel_launch(void* const* d_in, const int* in_sizes, int n_in,
                              void* d_out, int out_size, void* d_ws, size_t ws_size,
                              hipStream_t stream)
{
    const float* x  = (const float*)d_in[0];
    const float* Wq = (const float*)d_in[1];
    const float* Wk = (const float*)d_in[2];
    const float* Wv = (const float*)d_in[3];
    const float* Wo = (const float*)d_in[4];
    const float* bo = (const float*)d_in[5];
    float* out = (float*)d_out;

    u16* xb   = (u16*)d_ws;            // [8192][1024]
    u16* WTq  = xb + NQKV;             // [1024][1024] (n-major)
    u16* WTk  = WTq + NW;
    u16* WTv  = WTk + NW;
    u16* WTo  = WTv + NW;
    u16* Qb   = WTo + NW;              // [BH][T][64], pre-scaled
    u16* Kb   = Qb + NQKV;
    u16* Vb   = Kb + NQKV;
    u16* VTb  = Vb + NQKV;             // [BH][64][T]
    u16* ctxb = VTb + NQKV;            // [B][T][D]

    cvt_x_kernel<<<8192, 256, 0, stream>>>(x, xb);
    wt_cvt_kernel<<<dim3(16, 16, 4), 256, 0, stream>>>(Wq, Wk, Wv, Wo, WTq, WTk, WTv, WTo);
    qkv_gemm_kernel<<<dim3(64, 8, 3), 256, 0, stream>>>(xb, WTq, WTk, WTv, Qb, Kb, Vb);
    v_transpose_kernel<<<dim3(32, 64), 256, 0, stream>>>(Vb, VTb);
    attn_mfma_kernel<<<dim3(8, 64), 256, 0, stream>>>(Qb, Kb, VTb, ctxb);
    out_gemm_kernel<<<dim3(64, 8), 256, 0, stream>>>(ctxb, WTo, bo, out);
}